// Round 11
// baseline (642.537 us; speedup 1.0000x reference)
//
#include <hip/hip_runtime.h>
#include <hip/hip_bf16.h>
#include <math.h>

#define Bq   8
#define DINq 256
#define Nq   2048

typedef __attribute__((ext_vector_type(8))) short bf16x8v;
typedef __attribute__((ext_vector_type(4))) float f32x4v;

__device__ __forceinline__ unsigned short f2bf(float f) {
  union { float f; unsigned u; } v; v.f = f;
  unsigned r = v.u + 0x7fffu + ((v.u >> 16) & 1u);
  return (unsigned short)(r >> 16);
}
__device__ __forceinline__ float bf2f(unsigned short h) {
  union { unsigned u; float f; } v; v.u = ((unsigned)h) << 16;
  return v.f;
}

__device__ __forceinline__ void gld_lds16(const void* g, void* l) {
  __builtin_amdgcn_global_load_lds(
      (const __attribute__((address_space(1))) unsigned int*)g,
      (__attribute__((address_space(3))) unsigned int*)l, 16, 0, 0);
}

// 8 mask bits -> 8 bf16 (1.0/0.0) packed as bf16x8v, element e = bit e.
__device__ __forceinline__ bf16x8v expand_mask(unsigned m8) {
  union { unsigned u[4]; bf16x8v v; } r;
  unsigned lo4 = ((m8 & 0xFu) * 0x204081u) & 0x01010101u;
  unsigned hi4 = (((m8 >> 4) & 0xFu) * 0x204081u) & 0x01010101u;
  r.u[0] = ((lo4 & 0xFFu) | ((lo4 & 0xFF00u) << 8)) * 0x3F80u;
  r.u[1] = (((lo4 >> 16) & 0xFFu) | ((lo4 >> 24) << 16)) * 0x3F80u;
  r.u[2] = ((hi4 & 0xFFu) | ((hi4 & 0xFF00u) << 8)) * 0x3F80u;
  r.u[3] = (((hi4 >> 16) & 0xFFu) | ((hi4 >> 24) << 16)) * 0x3F80u;
  return r.v;
}

// ---- w123[k] = (W^T a1)[k], (W^T a2)[k], (W^T a3)[k] ----
__global__ void k_prep(const float* __restrict__ W, const float* __restrict__ a,
                       float* __restrict__ w123) {
  __shared__ float red[3][4][256];
  const int k = threadIdx.x & 255, dq = threadIdx.x >> 8;
  float s1 = 0.f, s2 = 0.f, s3 = 0.f;
  for (int d = dq * 64; d < dq * 64 + 64; ++d) {
    float w = W[d * DINq + k];
    s1 += w * a[d];
    s2 += w * a[DINq + d];
    s3 += w * a[2 * DINq + d];
  }
  red[0][dq][k] = s1; red[1][dq][k] = s2; red[2][dq][k] = s3;
  __syncthreads();
  if (threadIdx.x < 256) {
    w123[k]            = red[0][0][k] + red[0][1][k] + red[0][2][k] + red[0][3][k];
    w123[DINq + k]     = red[1][0][k] + red[1][1][k] + red[1][2][k] + red[1][3][k];
    w123[2 * DINq + k] = red[2][0][k] + red[2][1][k] + red[2][2][k] + red[2][3][k];
  }
}

// ---- WT[k][d] = W[d][k] ----
__global__ void k_transposeW(const float* __restrict__ W, float* __restrict__ WT) {
  int d = blockIdx.x, k = threadIdx.x;
  WT[(size_t)k * DINq + d] = W[(size_t)d * DINq + k];
}

// ---- hX (R9 v2) with x4 in-kernel repeat for counter surfacing ----
__global__ __launch_bounds__(256, 2) void k_hX(const float* __restrict__ x,
                     const float* __restrict__ WT, const float* __restrict__ w123,
                     unsigned short* __restrict__ Xhi, unsigned short* __restrict__ Xlo,
                     float* __restrict__ tA, float* __restrict__ siA,
                     float* __restrict__ sbA) {
  __shared__ float xs[64][32];
  __shared__ float ws[64][128];
  __shared__ float wls[3][256];
  __shared__ float Pd[3][16][32];
  __shared__ float Tt[32];
  const int tid = threadIdx.x;
  const int iq = tid & 15;
  const int dg = tid >> 4;
  const int i0 = blockIdx.x * 32;
  const int b = blockIdx.y;

  for (int n = tid; n < 768; n += 256) ((float*)wls)[n] = w123[n];

  for (int rep = 0; rep < 4; ++rep) {  // MEASUREMENT: x4 idempotent repeat
  float p1[2] = {0.f, 0.f}, p2[2] = {0.f, 0.f}, p3[2] = {0.f, 0.f};

#pragma unroll
  for (int dh = 0; dh < 2; ++dh) {
    float acc[2][8];
#pragma unroll
    for (int aa = 0; aa < 2; ++aa)
#pragma unroll
      for (int cc = 0; cc < 8; ++cc) acc[aa][cc] = 0.f;

    for (int kc = 0; kc < 4; ++kc) {
      __syncthreads();
#pragma unroll
      for (int n = 0; n < 8; ++n) {
        int idx = n * 256 + tid;
        int kk = idx >> 5, ii = idx & 31;
        xs[kk][ii] = x[((size_t)b * DINq + kc * 64 + kk) * Nq + i0 + ii];
      }
#pragma unroll
      for (int n = 0; n < 8; ++n) {
        int idx = n * 256 + tid;
        int kk = idx >> 5, c4 = (idx & 31) * 4;
        *(f32x4v*)&ws[kk][c4] =
            *(const f32x4v*)&WT[(size_t)(kc * 64 + kk) * DINq + dh * 128 + c4];
      }
      __syncthreads();
#pragma unroll 4
      for (int kk = 0; kk < 64; ++kk) {
        float xv0 = xs[kk][iq * 2], xv1 = xs[kk][iq * 2 + 1];
        f32x4v w0 = *(const f32x4v*)&ws[kk][dg * 8];
        f32x4v w1 = *(const f32x4v*)&ws[kk][dg * 8 + 4];
#pragma unroll
        for (int cc = 0; cc < 4; ++cc) {
          acc[0][cc]     += xv0 * w0[cc];
          acc[0][cc + 4] += xv0 * w1[cc];
          acc[1][cc]     += xv1 * w0[cc];
          acc[1][cc + 4] += xv1 * w1[cc];
        }
      }
      if (dh == 0) {
#pragma unroll
        for (int kap = 0; kap < 4; ++kap) {
          int kk = dg * 4 + kap;
          float xv0 = xs[kk][iq * 2], xv1 = xs[kk][iq * 2 + 1];
          float w3 = wls[2][kc * 64 + kk];
          float w1v = wls[0][kc * 64 + kk], w2v = wls[1][kc * 64 + kk];
          p3[0] += xv0 * w3;  p3[1] += xv1 * w3;
          p1[0] += xv0 * w1v; p1[1] += xv1 * w1v;
          p2[0] += xv0 * w2v; p2[1] += xv1 * w2v;
        }
      }
    }

    if (dh == 0) {
#pragma unroll
      for (int aa = 0; aa < 2; ++aa) {
        Pd[0][dg][iq * 2 + aa] = p1[aa];
        Pd[1][dg][iq * 2 + aa] = p2[aa];
        Pd[2][dg][iq * 2 + aa] = p3[aa];
      }
      __syncthreads();
      if (tid < 32) {
        float t = 0.f, s1 = 0.f, s2 = 0.f;
#pragma unroll
        for (int g = 0; g < 16; ++g) {
          s1 += Pd[0][g][tid]; s2 += Pd[1][g][tid]; t += Pd[2][g][tid];
        }
        Tt[tid] = t;
        tA[(size_t)b * Nq + i0 + tid] = t;
        siA[(size_t)b * Nq + i0 + tid] = s1;
        sbA[(size_t)b * Nq + i0 + tid] = s2;
      }
      __syncthreads();
    }

    const float tv0 = Tt[iq * 2], tv1 = Tt[iq * 2 + 1];
#pragma unroll
    for (int cc = 0; cc < 8; ++cc) {
      int d = dh * 128 + dg * 8 + cc;
      float X0 = tv0 * acc[0][cc];
      float X1 = tv1 * acc[1][cc];
      unsigned short h0 = f2bf(X0), h1 = f2bf(X1);
      unsigned short l0 = f2bf(X0 - bf2f(h0)), l1 = f2bf(X1 - bf2f(h1));
      size_t xoff = ((size_t)b * DINq + d) * Nq + i0 + iq * 2;
      *(ushort2*)&Xhi[xoff] = make_ushort2(h0, h1);
      *(ushort2*)&Xlo[xoff] = make_ushort2(l0, l1);
    }
  }
  }  // rep
}

// ---- bm[i][w] = bitmask of (adj[i][j]!=0), 32 j per word ----
__global__ void k_mask(const int* __restrict__ adj, unsigned* __restrict__ bm) {
  int wg = blockIdx.x * 256 + threadIdx.x;
  int i = wg >> 6, w = wg & 63, j0 = w * 32;
  const int4* ap = (const int4*)&adj[(size_t)i * Nq + j0];
  unsigned bits = 0;
#pragma unroll
  for (int q = 0; q < 8; ++q) {
    int4 a = ap[q];
    if (a.x) bits |= 1u << (q * 4);
    if (a.y) bits |= 1u << (q * 4 + 1);
    if (a.z) bits |= 1u << (q * 4 + 2);
    if (a.w) bits |= 1u << (q * 4 + 3);
  }
  bm[wg] = bits;
}

// ---- GEMM (R9, frozen) with x6 in-kernel repeat for counter surfacing ----
__global__ __launch_bounds__(256, 2) void k_gemm(const unsigned* __restrict__ bm,
                                                 const unsigned short* __restrict__ Xhi,
                                                 const unsigned short* __restrict__ Xlo,
                                                 float* __restrict__ sjp) {
  __shared__ __align__(16) unsigned short Bs[3][2][128 * 32];
  __shared__ unsigned bmlds[256 * 16];
  const int tid = threadIdx.x;
  const int lane = tid & 63;
  const int wave = tid >> 6;
  const int wm = wave >> 1, wc = wave & 1;
  const int wg = blockIdx.x;
  const int xcd = wg & 7;
  const int sub = wg >> 3;
  const int ct = xcd * 2 + (sub & 1);
  const int mt = (sub >> 1) & 7;
  const int ks = sub >> 4;
  const int i0 = mt * 256, c0 = ct * 128, kbase = ks * 512;
  const int r15 = lane & 15, kg = lane >> 4;
  const int kb = 16 * (kg ^ ((r15 >> 1) & 3));

  auto STAGE = [&](int buf, int t) {
    const int k0 = kbase + t * 32;
#pragma unroll
    for (int l = 0; l < 2; ++l) {
      const int pc = l * 256 + tid;
      const int row = pc >> 2, q = pc & 3;
      const int kc = 8 * (q ^ ((row >> 1) & 3));
      gld_lds16(&Xhi[(size_t)(c0 + row) * Nq + k0 + kc], &Bs[buf][0][pc * 8]);
      gld_lds16(&Xlo[(size_t)(c0 + row) * Nq + k0 + kc], &Bs[buf][1][pc * 8]);
    }
  };

  for (int rep = 0; rep < 6; ++rep) {  // MEASUREMENT: x6 idempotent repeat
  __syncthreads();
  {
    const int kw0 = kbase >> 5;
#pragma unroll
    for (int n = 0; n < 4; ++n) {
      int idx4 = n * 256 + tid;
      int r = idx4 >> 2, w4 = (idx4 & 3) * 4;
      uint4 v = *(const uint4*)&bm[(size_t)(i0 + r) * 64 + kw0 + w4];
      bmlds[r * 16 + ((w4 + 0) ^ (r & 15))] = v.x;
      bmlds[r * 16 + ((w4 + 1) ^ (r & 15))] = v.y;
      bmlds[r * 16 + ((w4 + 2) ^ (r & 15))] = v.z;
      bmlds[r * 16 + ((w4 + 3) ^ (r & 15))] = v.w;
    }
  }
  __syncthreads();

  f32x4v acc[8][4];
#pragma unroll
  for (int m = 0; m < 8; ++m)
#pragma unroll
    for (int n = 0; n < 4; ++n) acc[m][n] = (f32x4v)0.f;

  constexpr int NT = 16;
  STAGE(0, 0);
  STAGE(1, 1);
  int cb = 0, sb2 = 2;
  for (int t = 0; t < NT; ++t) {
    if (t + 1 < NT) {
      asm volatile("s_waitcnt vmcnt(4)" ::: "memory");
    } else {
      asm volatile("s_waitcnt vmcnt(0)" ::: "memory");
    }
    __builtin_amdgcn_sched_barrier(0);
    __builtin_amdgcn_s_barrier();
    __builtin_amdgcn_sched_barrier(0);
    if (t + 2 < NT) STAGE(sb2, t + 2);

    const char* Bh = (const char*)&Bs[cb][0][0];
    const char* Bl = (const char*)&Bs[cb][1][0];
    bf16x8v bfh[4], bfl[4];
#pragma unroll
    for (int n = 0; n < 4; ++n) {
      bfh[n] = *(const bf16x8v*)(Bh + (wc * 64 + n * 16 + r15) * 64 + kb);
      bfl[n] = *(const bf16x8v*)(Bl + (wc * 64 + n * 16 + r15) * 64 + kb);
    }
    const int jb = kbase + t * 32 + kg * 8;
#pragma unroll
    for (int m = 0; m < 8; ++m) {
      const int arow = wm * 128 + m * 16 + r15;
      unsigned wv = bmlds[arow * 16 + (t ^ (arow & 15))];
      unsigned m8 = (wv >> (kg * 8)) & 0xFFu;
      unsigned d = (unsigned)(i0 + arow - jb);
      if (d < 8u) m8 &= ~(1u << d);
      bf16x8v af = expand_mask(m8);
      __builtin_amdgcn_s_setprio(1);
#pragma unroll
      for (int n = 0; n < 4; ++n) {
        acc[m][n] = __builtin_amdgcn_mfma_f32_16x16x32_bf16(af, bfh[n], acc[m][n], 0, 0, 0);
        acc[m][n] = __builtin_amdgcn_mfma_f32_16x16x32_bf16(af, bfl[n], acc[m][n], 0, 0, 0);
      }
      __builtin_amdgcn_s_setprio(0);
    }
    cb = (cb == 2) ? 0 : cb + 1;
    sb2 = (sb2 == 2) ? 0 : sb2 + 1;
  }

  const int b = c0 >> 8;
  const int re = (lane >> 4) * 4, ce = lane & 15;
  float s[8][4];
#pragma unroll
  for (int m = 0; m < 8; ++m)
#pragma unroll
    for (int r = 0; r < 4; ++r) s[m][r] = 0.f;
#pragma unroll
  for (int n = 0; n < 4; ++n) {
    const size_t xrow = (size_t)(c0 + wc * 64 + n * 16 + ce) * Nq;
#pragma unroll
    for (int m = 0; m < 8; ++m) {
      const size_t ib = xrow + i0 + wm * 128 + m * 16 + re;
      ushort4 xh = *(const ushort4*)&Xhi[ib];
      ushort4 xl = *(const ushort4*)&Xlo[ib];
      s[m][0] += acc[m][n][0] * (bf2f(xh.x) + bf2f(xl.x));
      s[m][1] += acc[m][n][1] * (bf2f(xh.y) + bf2f(xl.y));
      s[m][2] += acc[m][n][2] * (bf2f(xh.z) + bf2f(xl.z));
      s[m][3] += acc[m][n][3] * (bf2f(xh.w) + bf2f(xl.w));
    }
  }
#pragma unroll
  for (int o = 1; o < 16; o <<= 1) {
#pragma unroll
    for (int m = 0; m < 8; ++m)
#pragma unroll
      for (int r = 0; r < 4; ++r) s[m][r] += __shfl_xor(s[m][r], o, 64);
  }
  if (ce == 0) {
    const int slice = (ct & 1) * 8 + ks * 2 + wc;
    float* sp = sjp + ((size_t)slice * Bq + b) * Nq;
#pragma unroll
    for (int m = 0; m < 8; ++m)
#pragma unroll
      for (int r = 0; r < 4; ++r)
        sp[i0 + wm * 128 + m * 16 + re + r] = s[m][r];
  }
  }  // rep
}

// ---- sjv[b,i] = sb[b,i] + (sum of 16 partial slices) / t[b,i] ----
__global__ void k_sjsum(const float* __restrict__ sbA, const float* __restrict__ tA,
                        const float* __restrict__ sjp, float* __restrict__ sjvA) {
  int idx = blockIdx.x * 256 + threadIdx.x;
  float s = 0.f;
#pragma unroll
  for (int sl = 0; sl < 16; ++sl) s += sjp[(size_t)sl * Bq * Nq + idx];
  sjvA[idx] = sbA[idx] + s / tA[idx];
}

// ---- softmax with x4 in-kernel repeat for counter surfacing ----
__global__ void k_softmax(const unsigned* __restrict__ bm, const float* __restrict__ siA,
                          const float* __restrict__ sjvA, float* __restrict__ out) {
  __shared__ float redm[4], reds[4];
  const int b = blockIdx.y, i = blockIdx.x, tid = threadIdx.x;
  const int wave = tid >> 6, lane = tid & 63;
  const float siv = siA[(size_t)b * Nq + i];
  const unsigned* brow = bm + (size_t)i * 64;
  const float* sjb = sjvA + (size_t)b * Nq;
  const int bit = tid & 31;

  for (int rep = 0; rep < 4; ++rep) {  // MEASUREMENT: x4 idempotent repeat
  float sc[8];
  float mx = -3.0e38f;
#pragma unroll
  for (int s = 0; s < 8; ++s) {
    int j = s * 256 + tid;
    float v = siv + sjb[j];
    v = v > 0.f ? v : 0.2f * v;
    unsigned wv = brow[j >> 5];
    v = ((wv >> bit) & 1u) ? v : -9.0e15f;
    sc[s] = v;
    mx = fmaxf(mx, v);
  }
#pragma unroll
  for (int o = 32; o >= 1; o >>= 1) mx = fmaxf(mx, __shfl_xor(mx, o, 64));
  if (lane == 0) redm[wave] = mx;
  __syncthreads();
  mx = fmaxf(fmaxf(redm[0], redm[1]), fmaxf(redm[2], redm[3]));
  float sum = 0.f, ex[8];
#pragma unroll
  for (int s = 0; s < 8; ++s) { ex[s] = expf(sc[s] - mx); sum += ex[s]; }
#pragma unroll
  for (int o = 32; o >= 1; o >>= 1) sum += __shfl_xor(sum, o, 64);
  if (lane == 0) reds[wave] = sum;
  __syncthreads();
  sum = reds[0] + reds[1] + reds[2] + reds[3];
  float inv = 1.f / sum;
  float* orow = out + ((size_t)b * Nq + i) * Nq;
#pragma unroll
  for (int s = 0; s < 8; ++s) orow[s * 256 + tid] = ex[s] * inv;
  __syncthreads();
  }  // rep
}

extern "C" void kernel_launch(void* const* d_in, const int* in_sizes, int n_in,
                              void* d_out, int out_size, void* d_ws, size_t ws_size,
                              hipStream_t stream) {
  const float* x = (const float*)d_in[0];
  const int* adj = (const int*)d_in[1];
  const float* W = (const float*)d_in[2];
  const float* a = (const float*)d_in[3];
  float* out = (float*)d_out;

  char* ws = (char*)d_ws;
  size_t off = 0;
  auto alloc = [&](size_t bytes) -> void* {
    void* p = ws + off;
    off += (bytes + 255) & ~(size_t)255;
    return p;
  };
  float* w123 = (float*)alloc(3 * DINq * sizeof(float));
  float* WT = (float*)alloc((size_t)DINq * DINq * sizeof(float));
  float* tA = (float*)alloc((size_t)Bq * Nq * sizeof(float));
  float* siA = (float*)alloc((size_t)Bq * Nq * sizeof(float));
  float* sbA = (float*)alloc((size_t)Bq * Nq * sizeof(float));
  float* sjvA = (float*)alloc((size_t)Bq * Nq * sizeof(float));
  float* sjp = (float*)alloc((size_t)16 * Bq * Nq * sizeof(float));
  unsigned short* Xhi = (unsigned short*)alloc((size_t)Nq * Nq * 2);
  unsigned short* Xlo = (unsigned short*)alloc((size_t)Nq * Nq * 2);
  unsigned* bm = (unsigned*)alloc((size_t)Nq * 64 * sizeof(unsigned));

  k_prep<<<dim3(1), dim3(1024), 0, stream>>>(W, a, w123);
  k_transposeW<<<dim3(DINq), dim3(DINq), 0, stream>>>(W, WT);
  k_hX<<<dim3(Nq / 32, Bq), dim3(256), 0, stream>>>(x, WT, w123, Xhi, Xlo, tA, siA, sbA);
  k_mask<<<dim3(Nq * 64 / 256), dim3(256), 0, stream>>>(adj, bm);
  k_gemm<<<dim3(512), dim3(256), 0, stream>>>(bm, Xhi, Xlo, sjp);
  k_sjsum<<<dim3(Bq * Nq / 256), dim3(256), 0, stream>>>(sbA, tA, sjp, sjvA);
  k_softmax<<<dim3(Nq, Bq), dim3(256), 0, stream>>>(bm, siA, sjvA, out);
}

// Round 12
// 361.771 us; speedup vs baseline: 1.7761x; 1.7761x over previous
//
#include <hip/hip_runtime.h>
#include <hip/hip_bf16.h>
#include <math.h>

#define Bq   8
#define DINq 256
#define Nq   2048

typedef __attribute__((ext_vector_type(8))) short bf16x8v;
typedef __attribute__((ext_vector_type(4))) float f32x4v;

__device__ __forceinline__ unsigned short f2bf(float f) {
  union { float f; unsigned u; } v; v.f = f;
  unsigned r = v.u + 0x7fffu + ((v.u >> 16) & 1u);
  return (unsigned short)(r >> 16);
}
__device__ __forceinline__ float bf2f(unsigned short h) {
  union { unsigned u; float f; } v; v.u = ((unsigned)h) << 16;
  return v.f;
}

__device__ __forceinline__ void gld_lds16(const void* g, void* l) {
  __builtin_amdgcn_global_load_lds(
      (const __attribute__((address_space(1))) unsigned int*)g,
      (__attribute__((address_space(3))) unsigned int*)l, 16, 0, 0);
}

// 8 mask bits -> 8 bf16 (1.0/0.0) packed as bf16x8v, element e = bit e.
__device__ __forceinline__ bf16x8v expand_mask(unsigned m8) {
  union { unsigned u[4]; bf16x8v v; } r;
  unsigned lo4 = ((m8 & 0xFu) * 0x204081u) & 0x01010101u;
  unsigned hi4 = (((m8 >> 4) & 0xFu) * 0x204081u) & 0x01010101u;
  r.u[0] = ((lo4 & 0xFFu) | ((lo4 & 0xFF00u) << 8)) * 0x3F80u;
  r.u[1] = (((lo4 >> 16) & 0xFFu) | ((lo4 >> 24) << 16)) * 0x3F80u;
  r.u[2] = ((hi4 & 0xFFu) | ((hi4 & 0xFF00u) << 8)) * 0x3F80u;
  r.u[3] = (((hi4 >> 16) & 0xFFu) | ((hi4 >> 24) << 16)) * 0x3F80u;
  return r.v;
}

// ---- w123[k] = (W^T a1)[k], (W^T a2)[k], (W^T a3)[k] ----
__global__ void k_prep(const float* __restrict__ W, const float* __restrict__ a,
                       float* __restrict__ w123) {
  __shared__ float red[3][4][256];
  const int k = threadIdx.x & 255, dq = threadIdx.x >> 8;
  float s1 = 0.f, s2 = 0.f, s3 = 0.f;
  for (int d = dq * 64; d < dq * 64 + 64; ++d) {
    float w = W[d * DINq + k];
    s1 += w * a[d];
    s2 += w * a[DINq + d];
    s3 += w * a[2 * DINq + d];
  }
  red[0][dq][k] = s1; red[1][dq][k] = s2; red[2][dq][k] = s3;
  __syncthreads();
  if (threadIdx.x < 256) {
    w123[k]            = red[0][0][k] + red[0][1][k] + red[0][2][k] + red[0][3][k];
    w123[DINq + k]     = red[1][0][k] + red[1][1][k] + red[1][2][k] + red[1][3][k];
    w123[2 * DINq + k] = red[2][0][k] + red[2][1][k] + red[2][2][k] + red[2][3][k];
  }
}

// ---- WT[k][d] = W[d][k] ----
__global__ void k_transposeW(const float* __restrict__ W, float* __restrict__ WT) {
  int d = blockIdx.x, k = threadIdx.x;
  WT[(size_t)k * DINq + d] = W[(size_t)d * DINq + k];
}

// ---- hX (R9, frozen): X^T = t*h hi/lo bf16; fused t/si/sb ----
__global__ __launch_bounds__(256, 2) void k_hX(const float* __restrict__ x,
                     const float* __restrict__ WT, const float* __restrict__ w123,
                     unsigned short* __restrict__ Xhi, unsigned short* __restrict__ Xlo,
                     float* __restrict__ tA, float* __restrict__ siA,
                     float* __restrict__ sbA) {
  __shared__ float xs[64][32];
  __shared__ float ws[64][128];
  __shared__ float wls[3][256];
  __shared__ float Pd[3][16][32];
  __shared__ float Tt[32];
  const int tid = threadIdx.x;
  const int iq = tid & 15;
  const int dg = tid >> 4;
  const int i0 = blockIdx.x * 32;
  const int b = blockIdx.y;

  for (int n = tid; n < 768; n += 256) ((float*)wls)[n] = w123[n];

  float p1[2] = {0.f, 0.f}, p2[2] = {0.f, 0.f}, p3[2] = {0.f, 0.f};

#pragma unroll
  for (int dh = 0; dh < 2; ++dh) {
    float acc[2][8];
#pragma unroll
    for (int aa = 0; aa < 2; ++aa)
#pragma unroll
      for (int cc = 0; cc < 8; ++cc) acc[aa][cc] = 0.f;

    for (int kc = 0; kc < 4; ++kc) {
      __syncthreads();
#pragma unroll
      for (int n = 0; n < 8; ++n) {
        int idx = n * 256 + tid;
        int kk = idx >> 5, ii = idx & 31;
        xs[kk][ii] = x[((size_t)b * DINq + kc * 64 + kk) * Nq + i0 + ii];
      }
#pragma unroll
      for (int n = 0; n < 8; ++n) {
        int idx = n * 256 + tid;
        int kk = idx >> 5, c4 = (idx & 31) * 4;
        *(f32x4v*)&ws[kk][c4] =
            *(const f32x4v*)&WT[(size_t)(kc * 64 + kk) * DINq + dh * 128 + c4];
      }
      __syncthreads();
#pragma unroll 4
      for (int kk = 0; kk < 64; ++kk) {
        float xv0 = xs[kk][iq * 2], xv1 = xs[kk][iq * 2 + 1];
        f32x4v w0 = *(const f32x4v*)&ws[kk][dg * 8];
        f32x4v w1 = *(const f32x4v*)&ws[kk][dg * 8 + 4];
#pragma unroll
        for (int cc = 0; cc < 4; ++cc) {
          acc[0][cc]     += xv0 * w0[cc];
          acc[0][cc + 4] += xv0 * w1[cc];
          acc[1][cc]     += xv1 * w0[cc];
          acc[1][cc + 4] += xv1 * w1[cc];
        }
      }
      if (dh == 0) {
#pragma unroll
        for (int kap = 0; kap < 4; ++kap) {
          int kk = dg * 4 + kap;
          float xv0 = xs[kk][iq * 2], xv1 = xs[kk][iq * 2 + 1];
          float w3 = wls[2][kc * 64 + kk];
          float w1v = wls[0][kc * 64 + kk], w2v = wls[1][kc * 64 + kk];
          p3[0] += xv0 * w3;  p3[1] += xv1 * w3;
          p1[0] += xv0 * w1v; p1[1] += xv1 * w1v;
          p2[0] += xv0 * w2v; p2[1] += xv1 * w2v;
        }
      }
    }

    if (dh == 0) {
#pragma unroll
      for (int aa = 0; aa < 2; ++aa) {
        Pd[0][dg][iq * 2 + aa] = p1[aa];
        Pd[1][dg][iq * 2 + aa] = p2[aa];
        Pd[2][dg][iq * 2 + aa] = p3[aa];
      }
      __syncthreads();
      if (tid < 32) {
        float t = 0.f, s1 = 0.f, s2 = 0.f;
#pragma unroll
        for (int g = 0; g < 16; ++g) {
          s1 += Pd[0][g][tid]; s2 += Pd[1][g][tid]; t += Pd[2][g][tid];
        }
        Tt[tid] = t;
        tA[(size_t)b * Nq + i0 + tid] = t;
        siA[(size_t)b * Nq + i0 + tid] = s1;
        sbA[(size_t)b * Nq + i0 + tid] = s2;
      }
      __syncthreads();
    }

    const float tv0 = Tt[iq * 2], tv1 = Tt[iq * 2 + 1];
#pragma unroll
    for (int cc = 0; cc < 8; ++cc) {
      int d = dh * 128 + dg * 8 + cc;
      float X0 = tv0 * acc[0][cc];
      float X1 = tv1 * acc[1][cc];
      unsigned short h0 = f2bf(X0), h1 = f2bf(X1);
      unsigned short l0 = f2bf(X0 - bf2f(h0)), l1 = f2bf(X1 - bf2f(h1));
      size_t xoff = ((size_t)b * DINq + d) * Nq + i0 + iq * 2;
      *(ushort2*)&Xhi[xoff] = make_ushort2(h0, h1);
      *(ushort2*)&Xlo[xoff] = make_ushort2(l0, l1);
    }
  }
}

// ---- bm[i][w] = bitmask of (adj[i][j]!=0), 32 j per word ----
__global__ void k_mask(const int* __restrict__ adj, unsigned* __restrict__ bm) {
  int wg = blockIdx.x * 256 + threadIdx.x;
  int i = wg >> 6, w = wg & 63, j0 = w * 32;
  const int4* ap = (const int4*)&adj[(size_t)i * Nq + j0];
  unsigned bits = 0;
#pragma unroll
  for (int q = 0; q < 8; ++q) {
    int4 a = ap[q];
    if (a.x) bits |= 1u << (q * 4);
    if (a.y) bits |= 1u << (q * 4 + 1);
    if (a.z) bits |= 1u << (q * 4 + 2);
    if (a.w) bits |= 1u << (q * 4 + 3);
  }
  bm[wg] = bits;
}

// ---- GEMM v4: parity-staged (hi/lo alternate per t-tile), 36KB LDS,
//      4 blocks/CU, K-split x8 (1024 blocks), ct-grouped per XCD,
//      tri-buffer counted vmcnt, LDS-repacked coalesced sjp writes ----
__global__ __launch_bounds__(256, 4) void k_gemm(const unsigned* __restrict__ bm,
                                                 const unsigned short* __restrict__ Xhi,
                                                 const unsigned short* __restrict__ Xlo,
                                                 float* __restrict__ sjp) {
  __shared__ __align__(16) unsigned short Bs[3][128 * 32];  // 24 KB
  __shared__ unsigned bmlds[256 * 8];                       // 8 KB
  __shared__ float swb[8][128];                             // 4 KB
  const int tid = threadIdx.x;
  const int lane = tid & 63;
  const int wave = tid >> 6;
  const int wm = wave >> 1, wc = wave & 1;
  // 1024 blocks: xcd-major round-robin; per XCD: ct in {2x,2x+1}, mt x8, ks x8
  const int wg = blockIdx.x;
  const int xcd = wg & 7;
  const int sub = wg >> 3;            // [0,128)
  const int ct = xcd * 2 + (sub & 1);
  const int mt = (sub >> 1) & 7;
  const int ks = sub >> 4;            // [0,8)
  const int i0 = mt * 256, c0 = ct * 128, kbase = ks * 256;
  const int r15 = lane & 15, kg = lane >> 4;
  const int kb = 16 * (kg ^ ((r15 >> 1) & 3));

  // stage mask bits: 256 rows x 8 words (K=256), xor-swizzled by (row&7)
  {
    const int kw0 = kbase >> 5;       // 8 words per row
#pragma unroll
    for (int n = 0; n < 2; ++n) {
      int idx4 = n * 256 + tid;
      int r = idx4 >> 1, w4 = (idx4 & 1) * 4;
      uint4 v = *(const uint4*)&bm[(size_t)(i0 + r) * 64 + kw0 + w4];
      bmlds[r * 8 + ((w4 + 0) ^ (r & 7))] = v.x;
      bmlds[r * 8 + ((w4 + 1) ^ (r & 7))] = v.y;
      bmlds[r * 8 + ((w4 + 2) ^ (r & 7))] = v.z;
      bmlds[r * 8 + ((w4 + 3) ^ (r & 7))] = v.w;
    }
  }
  __syncthreads();

  f32x4v acc[8][4];
#pragma unroll
  for (int m = 0; m < 8; ++m)
#pragma unroll
    for (int n = 0; n < 4; ++n) acc[m][n] = (f32x4v)0.f;

  // STAGE one parity-tile: t even -> Xhi k-slice t/2, t odd -> Xlo k-slice t/2.
  auto STAGE = [&](int buf, int t) {
    const unsigned short* __restrict__ src = (t & 1) ? Xlo : Xhi;
    const int k0 = kbase + (t >> 1) * 32;
#pragma unroll
    for (int l = 0; l < 2; ++l) {
      const int pc = l * 256 + tid;
      const int row = pc >> 2, q = pc & 3;
      const int kc = 8 * (q ^ ((row >> 1) & 3));
      gld_lds16(&src[(size_t)(c0 + row) * Nq + k0 + kc], &Bs[buf][pc * 8]);
    }
  };

  constexpr int NT = 16;  // 8 k-slices x 2 parities
  STAGE(0, 0);
  STAGE(1, 1);
  int cb = 0, sb2 = 2;
  for (int t = 0; t < NT; ++t) {
    if (t + 1 < NT) {
      asm volatile("s_waitcnt vmcnt(2)" ::: "memory");
    } else {
      asm volatile("s_waitcnt vmcnt(0)" ::: "memory");
    }
    __builtin_amdgcn_sched_barrier(0);
    __builtin_amdgcn_s_barrier();
    __builtin_amdgcn_sched_barrier(0);
    if (t + 2 < NT) STAGE(sb2, t + 2);

    const char* Bb = (const char*)&Bs[cb][0];
    bf16x8v bf[4];
#pragma unroll
    for (int n = 0; n < 4; ++n)
      bf[n] = *(const bf16x8v*)(Bb + (wc * 64 + n * 16 + r15) * 64 + kb);
    const int kch = t >> 1;
    const int jb = kbase + kch * 32 + kg * 8;
#pragma unroll
    for (int m = 0; m < 8; ++m) {
      const int arow = wm * 128 + m * 16 + r15;
      unsigned wv = bmlds[arow * 8 + (kch ^ (arow & 7))];
      unsigned m8 = (wv >> (kg * 8)) & 0xFFu;
      unsigned d = (unsigned)(i0 + arow - jb);
      if (d < 8u) m8 &= ~(1u << d);
      bf16x8v af = expand_mask(m8);
      __builtin_amdgcn_s_setprio(1);
#pragma unroll
      for (int n = 0; n < 4; ++n)
        acc[m][n] = __builtin_amdgcn_mfma_f32_16x16x32_bf16(af, bf[n], acc[m][n], 0, 0, 0);
      __builtin_amdgcn_s_setprio(0);
    }
    cb = (cb == 2) ? 0 : cb + 1;
    sb2 = (sb2 == 2) ? 0 : sb2 + 1;
  }

  // Fused epilogue: partial = sum_d acc * (Xhi+Xlo); division by t in k_sjsum.
  const int b = c0 >> 8;
  const int re = (lane >> 4) * 4, ce = lane & 15;
  float s[8][4];
#pragma unroll
  for (int m = 0; m < 8; ++m)
#pragma unroll
    for (int r = 0; r < 4; ++r) s[m][r] = 0.f;
#pragma unroll
  for (int n = 0; n < 4; ++n) {
    const size_t xrow = (size_t)(c0 + wc * 64 + n * 16 + ce) * Nq;
#pragma unroll
    for (int m = 0; m < 8; ++m) {
      const size_t ib = xrow + i0 + wm * 128 + m * 16 + re;
      ushort4 xh = *(const ushort4*)&Xhi[ib];
      ushort4 xl = *(const ushort4*)&Xlo[ib];
      s[m][0] += acc[m][n][0] * (bf2f(xh.x) + bf2f(xl.x));
      s[m][1] += acc[m][n][1] * (bf2f(xh.y) + bf2f(xl.y));
      s[m][2] += acc[m][n][2] * (bf2f(xh.z) + bf2f(xl.z));
      s[m][3] += acc[m][n][3] * (bf2f(xh.w) + bf2f(xl.w));
    }
  }
#pragma unroll
  for (int o = 1; o < 16; o <<= 1) {
#pragma unroll
    for (int m = 0; m < 8; ++m)
#pragma unroll
      for (int r = 0; r < 4; ++r) s[m][r] += __shfl_xor(s[m][r], o, 64);
  }
  // LDS repack -> two coalesced 256B stores per wave (kills write-allocate RMW)
  if (ce == 0) {
#pragma unroll
    for (int m = 0; m < 8; ++m)
#pragma unroll
      for (int r = 0; r < 4; ++r)
        swb[wave][m * 16 + re + r] = s[m][r];
  }
  __builtin_amdgcn_s_barrier();  // wave-local would suffice; barrier is safe
  {
    const int slice = (ct & 1) * 16 + ks * 2 + wc;
    float* sp = sjp + ((size_t)slice * Bq + b) * Nq + i0 + wm * 128;
    sp[lane] = swb[wave][lane];
    sp[64 + lane] = swb[wave][64 + lane];
  }
}

// ---- sjv[b,i] = sb[b,i] + (sum of 32 partial slices) / t[b,i] ----
__global__ void k_sjsum(const float* __restrict__ sbA, const float* __restrict__ tA,
                        const float* __restrict__ sjp, float* __restrict__ sjvA) {
  int idx = blockIdx.x * 256 + threadIdx.x;
  float s = 0.f;
#pragma unroll
  for (int sl = 0; sl < 32; ++sl) s += sjp[(size_t)sl * Bq * Nq + idx];
  sjvA[idx] = sbA[idx] + s / tA[idx];
}

// ---- out[b,i,:] = softmax_j( mask(bm, lrelu(si[b,i] + sjv[b,j])) ) ----
__global__ void k_softmax(const unsigned* __restrict__ bm, const float* __restrict__ siA,
                          const float* __restrict__ sjvA, float* __restrict__ out) {
  const int b = blockIdx.y, i = blockIdx.x, tid = threadIdx.x;
  const float siv = siA[(size_t)b * Nq + i];
  const unsigned* brow = bm + (size_t)i * 64;
  const float* sjb = sjvA + (size_t)b * Nq;
  const int bit = tid & 31;
  float sc[8];
  float mx = -3.0e38f;
#pragma unroll
  for (int s = 0; s < 8; ++s) {
    int j = s * 256 + tid;
    float v = siv + sjb[j];
    v = v > 0.f ? v : 0.2f * v;
    unsigned wv = brow[j >> 5];
    v = ((wv >> bit) & 1u) ? v : -9.0e15f;
    sc[s] = v;
    mx = fmaxf(mx, v);
  }
#pragma unroll
  for (int o = 32; o >= 1; o >>= 1) mx = fmaxf(mx, __shfl_xor(mx, o, 64));
  __shared__ float redm[4], reds[4];
  const int wave = tid >> 6, lane = tid & 63;
  if (lane == 0) redm[wave] = mx;
  __syncthreads();
  mx = fmaxf(fmaxf(redm[0], redm[1]), fmaxf(redm[2], redm[3]));
  float sum = 0.f, ex[8];
#pragma unroll
  for (int s = 0; s < 8; ++s) { ex[s] = expf(sc[s] - mx); sum += ex[s]; }
#pragma unroll
  for (int o = 32; o >= 1; o >>= 1) sum += __shfl_xor(sum, o, 64);
  if (lane == 0) reds[wave] = sum;
  __syncthreads();
  sum = reds[0] + reds[1] + reds[2] + reds[3];
  float inv = 1.f / sum;
  float* orow = out + ((size_t)b * Nq + i) * Nq;
#pragma unroll
  for (int s = 0; s < 8; ++s) orow[s * 256 + tid] = ex[s] * inv;
}

extern "C" void kernel_launch(void* const* d_in, const int* in_sizes, int n_in,
                              void* d_out, int out_size, void* d_ws, size_t ws_size,
                              hipStream_t stream) {
  const float* x = (const float*)d_in[0];
  const int* adj = (const int*)d_in[1];
  const float* W = (const float*)d_in[2];
  const float* a = (const float*)d_in[3];
  float* out = (float*)d_out;

  char* ws = (char*)d_ws;
  size_t off = 0;
  auto alloc = [&](size_t bytes) -> void* {
    void* p = ws + off;
    off += (bytes + 255) & ~(size_t)255;
    return p;
  };
  float* w123 = (float*)alloc(3 * DINq * sizeof(float));
  float* WT = (float*)alloc((size_t)DINq * DINq * sizeof(float));
  float* tA = (float*)alloc((size_t)Bq * Nq * sizeof(float));
  float* siA = (float*)alloc((size_t)Bq * Nq * sizeof(float));
  float* sbA = (float*)alloc((size_t)Bq * Nq * sizeof(float));
  float* sjvA = (float*)alloc((size_t)Bq * Nq * sizeof(float));
  float* sjp = (float*)alloc((size_t)32 * Bq * Nq * sizeof(float));
  unsigned short* Xhi = (unsigned short*)alloc((size_t)Nq * Nq * 2);
  unsigned short* Xlo = (unsigned short*)alloc((size_t)Nq * Nq * 2);
  unsigned* bm = (unsigned*)alloc((size_t)Nq * 64 * sizeof(unsigned));

  k_prep<<<dim3(1), dim3(1024), 0, stream>>>(W, a, w123);
  k_transposeW<<<dim3(DINq), dim3(DINq), 0, stream>>>(W, WT);
  k_hX<<<dim3(Nq / 32, Bq), dim3(256), 0, stream>>>(x, WT, w123, Xhi, Xlo, tA, siA, sbA);
  k_mask<<<dim3(Nq * 64 / 256), dim3(256), 0, stream>>>(adj, bm);
  k_gemm<<<dim3(1024), dim3(256), 0, stream>>>(bm, Xhi, Xlo, sjp);
  k_sjsum<<<dim3(Bq * Nq / 256), dim3(256), 0, stream>>>(sbA, tA, sjp, sjvA);
  k_softmax<<<dim3(Nq, Bq), dim3(256), 0, stream>>>(bm, siA, sjvA, out);
}

// Round 13
// 146.738 us; speedup vs baseline: 4.3788x; 2.4654x over previous
//
#include <hip/hip_runtime.h>
#include <hip/hip_bf16.h>
#include <math.h>

#define Bq   8
#define DINq 256
#define Nq   2048

typedef __attribute__((ext_vector_type(8))) short bf16x8v;
typedef __attribute__((ext_vector_type(4))) float f32x4v;

__device__ __forceinline__ unsigned short f2bf(float f) {
  union { float f; unsigned u; } v; v.f = f;
  unsigned r = v.u + 0x7fffu + ((v.u >> 16) & 1u);
  return (unsigned short)(r >> 16);
}
__device__ __forceinline__ float bf2f(unsigned short h) {
  union { unsigned u; float f; } v; v.u = ((unsigned)h) << 16;
  return v.f;
}

__device__ __forceinline__ void gld_lds16(const void* g, void* l) {
  __builtin_amdgcn_global_load_lds(
      (const __attribute__((address_space(1))) unsigned int*)g,
      (__attribute__((address_space(3))) unsigned int*)l, 16, 0, 0);
}

// 8 mask bits -> 8 bf16 (1.0/0.0) packed as bf16x8v, element e = bit e.
__device__ __forceinline__ bf16x8v expand_mask(unsigned m8) {
  union { unsigned u[4]; bf16x8v v; } r;
  unsigned lo4 = ((m8 & 0xFu) * 0x204081u) & 0x01010101u;
  unsigned hi4 = (((m8 >> 4) & 0xFu) * 0x204081u) & 0x01010101u;
  r.u[0] = ((lo4 & 0xFFu) | ((lo4 & 0xFF00u) << 8)) * 0x3F80u;
  r.u[1] = (((lo4 >> 16) & 0xFFu) | ((lo4 >> 24) << 16)) * 0x3F80u;
  r.u[2] = ((hi4 & 0xFFu) | ((hi4 & 0xFF00u) << 8)) * 0x3F80u;
  r.u[3] = (((hi4 >> 16) & 0xFFu) | ((hi4 >> 24) << 16)) * 0x3F80u;
  return r.v;
}

// ---- w123[k] = (W^T a1)[k], (W^T a2)[k], (W^T a3)[k] ----
__global__ void k_prep(const float* __restrict__ W, const float* __restrict__ a,
                       float* __restrict__ w123) {
  __shared__ float red[3][4][256];
  const int k = threadIdx.x & 255, dq = threadIdx.x >> 8;
  float s1 = 0.f, s2 = 0.f, s3 = 0.f;
  for (int d = dq * 64; d < dq * 64 + 64; ++d) {
    float w = W[d * DINq + k];
    s1 += w * a[d];
    s2 += w * a[DINq + d];
    s3 += w * a[2 * DINq + d];
  }
  red[0][dq][k] = s1; red[1][dq][k] = s2; red[2][dq][k] = s3;
  __syncthreads();
  if (threadIdx.x < 256) {
    w123[k]            = red[0][0][k] + red[0][1][k] + red[0][2][k] + red[0][3][k];
    w123[DINq + k]     = red[1][0][k] + red[1][1][k] + red[1][2][k] + red[1][3][k];
    w123[2 * DINq + k] = red[2][0][k] + red[2][1][k] + red[2][2][k] + red[2][3][k];
  }
}

// ---- WT[k][d] = W[d][k] ----
__global__ void k_transposeW(const float* __restrict__ W, float* __restrict__ WT) {
  int d = blockIdx.x, k = threadIdx.x;
  WT[(size_t)k * DINq + d] = W[(size_t)d * DINq + k];
}

// ---- hX v4: 4i x 8d register tile, full d=256 per pass (ws 64KB), 2 blocks/CU.
//      X^T[(b,d)][i] = t[b,i]*h[b,i,d] hi/lo bf16; wave0 computes t/si/sb. ----
__global__ __launch_bounds__(256, 2) void k_hX(const float* __restrict__ x,
                     const float* __restrict__ WT, const float* __restrict__ w123,
                     unsigned short* __restrict__ Xhi, unsigned short* __restrict__ Xlo,
                     float* __restrict__ tA, float* __restrict__ siA,
                     float* __restrict__ sbA) {
  __shared__ float xs[64][32];    // 8 KB   (k x i)
  __shared__ float ws[64][256];   // 64 KB  (k x d)
  __shared__ float wls[768];      // 3 KB
  __shared__ float Tt[32];
  const int tid = threadIdx.x;
  const int iq = tid & 7;         // 8 groups x 4 i = 32 i
  const int dg = tid >> 3;        // 32 groups x 8 d = 256 d
  const int i0 = blockIdx.x * 32;
  const int b = blockIdx.y;
  const int lane = tid & 63;
  const bool w0 = (tid < 64);
  const int ti = lane & 31;         // i owned by wave0 lane
  const int khalf = (lane >> 5) * 32;

  for (int n = tid; n < 768; n += 256) wls[n] = w123[n];

  float acc[4][8];
#pragma unroll
  for (int e = 0; e < 4; ++e)
#pragma unroll
    for (int cc = 0; cc < 8; ++cc) acc[e][cc] = 0.f;
  float p1 = 0.f, p2 = 0.f, p3 = 0.f;

  for (int kc = 0; kc < 4; ++kc) {
    __syncthreads();
    // stage xs (8 KB): 2 x gld16 per thread, dest linear in tid
#pragma unroll
    for (int l = 0; l < 2; ++l) {
      int c = l * 256 + tid;
      int r = c >> 3, ch = c & 7;
      gld_lds16(&x[((size_t)b * DINq + kc * 64 + r) * Nq + i0 + ch * 4], &xs[r][ch * 4]);
    }
    // stage ws (64 KB): 16 x gld16 per thread, dest linear in tid
#pragma unroll
    for (int l = 0; l < 16; ++l) {
      int c = l * 256 + tid;
      int r = c >> 6, ch = c & 63;
      gld_lds16(&WT[(size_t)(kc * 64 + r) * DINq + ch * 4], &ws[r][ch * 4]);
    }
    asm volatile("s_waitcnt vmcnt(0)" ::: "memory");
    __syncthreads();
#pragma unroll 4
    for (int kk = 0; kk < 64; ++kk) {
      f32x4v xv = *(const f32x4v*)&xs[kk][iq * 4];
      f32x4v wv0 = *(const f32x4v*)&ws[kk][dg * 8];
      f32x4v wv1 = *(const f32x4v*)&ws[kk][dg * 8 + 4];
#pragma unroll
      for (int e = 0; e < 4; ++e) {
#pragma unroll
        for (int cc = 0; cc < 4; ++cc) {
          acc[e][cc]     += xv[e] * wv0[cc];
          acc[e][cc + 4] += xv[e] * wv1[cc];
        }
      }
    }
    if (w0) {
      // t/si/sb partials: lane ti owns i, k-half split across lane>=32
#pragma unroll 4
      for (int k2 = 0; k2 < 32; ++k2) {
        int kk = khalf + k2;
        float xv = xs[kk][ti];
        p1 += xv * wls[kc * 64 + kk];
        p2 += xv * wls[256 + kc * 64 + kk];
        p3 += xv * wls[512 + kc * 64 + kk];
      }
    }
  }

  if (w0) {
    p1 += __shfl_xor(p1, 32, 64);
    p2 += __shfl_xor(p2, 32, 64);
    p3 += __shfl_xor(p3, 32, 64);
    if (lane < 32) {
      Tt[lane] = p3;
      tA[(size_t)b * Nq + i0 + lane] = p3;
      siA[(size_t)b * Nq + i0 + lane] = p1;
      sbA[(size_t)b * Nq + i0 + lane] = p2;
    }
  }
  __syncthreads();

  float tv[4];
#pragma unroll
  for (int e = 0; e < 4; ++e) tv[e] = Tt[iq * 4 + e];

#pragma unroll
  for (int cc = 0; cc < 8; ++cc) {
    const int d = dg * 8 + cc;
    unsigned short hv[4], lv[4];
#pragma unroll
    for (int e = 0; e < 4; ++e) {
      float Xv = tv[e] * acc[e][cc];
      unsigned short hs = f2bf(Xv);
      hv[e] = hs;
      lv[e] = f2bf(Xv - bf2f(hs));
    }
    size_t off = ((size_t)b * DINq + d) * Nq + i0 + iq * 4;
    *(ushort4*)&Xhi[off] = make_ushort4(hv[0], hv[1], hv[2], hv[3]);
    *(ushort4*)&Xlo[off] = make_ushort4(lv[0], lv[1], lv[2], lv[3]);
  }
}

// ---- bm[i][w] = bitmask of (adj[i][j]!=0), 32 j per word ----
__global__ void k_mask(const int* __restrict__ adj, unsigned* __restrict__ bm) {
  int wg = blockIdx.x * 256 + threadIdx.x;
  int i = wg >> 6, w = wg & 63, j0 = w * 32;
  const int4* ap = (const int4*)&adj[(size_t)i * Nq + j0];
  unsigned bits = 0;
#pragma unroll
  for (int q = 0; q < 8; ++q) {
    int4 a = ap[q];
    if (a.x) bits |= 1u << (q * 4);
    if (a.y) bits |= 1u << (q * 4 + 1);
    if (a.z) bits |= 1u << (q * 4 + 2);
    if (a.w) bits |= 1u << (q * 4 + 3);
  }
  bm[wg] = bits;
}

// ---- GEMM v5: tile 128(M)x128(C), 4 waves (2x2), acc[4][4]=64 VGPR (no spill),
//      parity-staged hi/lo, 33KB LDS -> 4 blocks/CU, K-split x4 (1024 blocks),
//      ct-grouped per XCD, tri-buffer counted vmcnt, coalesced sjp writes ----
__global__ __launch_bounds__(256, 4) void k_gemm(const unsigned* __restrict__ bm,
                                                 const unsigned short* __restrict__ Xhi,
                                                 const unsigned short* __restrict__ Xlo,
                                                 float* __restrict__ sjp) {
  __shared__ __align__(16) unsigned short Bs[3][128 * 32];  // 24 KB
  __shared__ unsigned bmlds[128 * 16];                      // 8 KB
  __shared__ float swb[4][64];                              // 1 KB
  const int tid = threadIdx.x;
  const int lane = tid & 63;
  const int wave = tid >> 6;
  const int wm = wave >> 1, wc = wave & 1;
  // 1024 blocks: per XCD: ct in {2x,2x+1}, mt x16, ks x4
  const int wg = blockIdx.x;
  const int xcd = wg & 7;
  const int sub = wg >> 3;            // [0,128)
  const int ct = xcd * 2 + (sub & 1);
  const int mt = (sub >> 1) & 15;
  const int ks = sub >> 5;            // [0,4)
  const int i0 = mt * 128, c0 = ct * 128, kbase = ks * 512;
  const int r15 = lane & 15, kg = lane >> 4;
  const int kb = 16 * (kg ^ ((r15 >> 1) & 3));

  // stage mask bits: 128 rows x 16 words (K=512), xor-swizzled by (row&15)
  {
    const int kw0 = kbase >> 5;
#pragma unroll
    for (int n = 0; n < 2; ++n) {
      int idx4 = n * 256 + tid;
      int r = idx4 >> 2, w4 = (idx4 & 3) * 4;
      uint4 v = *(const uint4*)&bm[(size_t)(i0 + r) * 64 + kw0 + w4];
      bmlds[r * 16 + ((w4 + 0) ^ (r & 15))] = v.x;
      bmlds[r * 16 + ((w4 + 1) ^ (r & 15))] = v.y;
      bmlds[r * 16 + ((w4 + 2) ^ (r & 15))] = v.z;
      bmlds[r * 16 + ((w4 + 3) ^ (r & 15))] = v.w;
    }
  }
  __syncthreads();

  f32x4v acc[4][4];
#pragma unroll
  for (int m = 0; m < 4; ++m)
#pragma unroll
    for (int n = 0; n < 4; ++n) acc[m][n] = (f32x4v)0.f;

  // STAGE one parity-tile: t even -> Xhi k-slice t/2, t odd -> Xlo k-slice t/2.
  auto STAGE = [&](int buf, int t) {
    const unsigned short* __restrict__ src = (t & 1) ? Xlo : Xhi;
    const int k0 = kbase + (t >> 1) * 32;
#pragma unroll
    for (int l = 0; l < 2; ++l) {
      const int pc = l * 256 + tid;
      const int row = pc >> 2, q = pc & 3;
      const int kc = 8 * (q ^ ((row >> 1) & 3));
      gld_lds16(&src[(size_t)(c0 + row) * Nq + k0 + kc], &Bs[buf][pc * 8]);
    }
  };

  constexpr int NT = 32;  // 16 k-slices x 2 parities
  STAGE(0, 0);
  STAGE(1, 1);
  int cb = 0, sb2 = 2;
  for (int t = 0; t < NT; ++t) {
    if (t + 1 < NT) {
      asm volatile("s_waitcnt vmcnt(2)" ::: "memory");
    } else {
      asm volatile("s_waitcnt vmcnt(0)" ::: "memory");
    }
    __builtin_amdgcn_sched_barrier(0);
    __builtin_amdgcn_s_barrier();
    __builtin_amdgcn_sched_barrier(0);
    if (t + 2 < NT) STAGE(sb2, t + 2);

    const char* Bb = (const char*)&Bs[cb][0];
    bf16x8v bf[4];
#pragma unroll
    for (int n = 0; n < 4; ++n)
      bf[n] = *(const bf16x8v*)(Bb + (wc * 64 + n * 16 + r15) * 64 + kb);
    const int kch = t >> 1;
    const int jb = kbase + kch * 32 + kg * 8;
#pragma unroll
    for (int m = 0; m < 4; ++m) {
      const int arow = wm * 64 + m * 16 + r15;
      unsigned wv = bmlds[arow * 16 + (kch ^ (arow & 15))];
      unsigned m8 = (wv >> (kg * 8)) & 0xFFu;
      unsigned d = (unsigned)(i0 + arow - jb);
      if (d < 8u) m8 &= ~(1u << d);
      bf16x8v af = expand_mask(m8);
      __builtin_amdgcn_s_setprio(1);
#pragma unroll
      for (int n = 0; n < 4; ++n)
        acc[m][n] = __builtin_amdgcn_mfma_f32_16x16x32_bf16(af, bf[n], acc[m][n], 0, 0, 0);
      __builtin_amdgcn_s_setprio(0);
    }
    cb = (cb == 2) ? 0 : cb + 1;
    sb2 = (sb2 == 2) ? 0 : sb2 + 1;
  }

  // Fused epilogue: partial = sum_d acc * (Xhi+Xlo); division by t in k_sjsum.
  const int b = c0 >> 8;
  const int re = (lane >> 4) * 4, ce = lane & 15;
  float s[4][4];
#pragma unroll
  for (int m = 0; m < 4; ++m)
#pragma unroll
    for (int r = 0; r < 4; ++r) s[m][r] = 0.f;
#pragma unroll
  for (int n = 0; n < 4; ++n) {
    const size_t xrow = (size_t)(c0 + wc * 64 + n * 16 + ce) * Nq;
#pragma unroll
    for (int m = 0; m < 4; ++m) {
      const size_t ib = xrow + i0 + wm * 64 + m * 16 + re;
      ushort4 xh = *(const ushort4*)&Xhi[ib];
      ushort4 xl = *(const ushort4*)&Xlo[ib];
      s[m][0] += acc[m][n][0] * (bf2f(xh.x) + bf2f(xl.x));
      s[m][1] += acc[m][n][1] * (bf2f(xh.y) + bf2f(xl.y));
      s[m][2] += acc[m][n][2] * (bf2f(xh.z) + bf2f(xl.z));
      s[m][3] += acc[m][n][3] * (bf2f(xh.w) + bf2f(xl.w));
    }
  }
#pragma unroll
  for (int o = 1; o < 16; o <<= 1) {
#pragma unroll
    for (int m = 0; m < 4; ++m)
#pragma unroll
      for (int r = 0; r < 4; ++r) s[m][r] += __shfl_xor(s[m][r], o, 64);
  }
  if (ce == 0) {
#pragma unroll
    for (int m = 0; m < 4; ++m)
#pragma unroll
      for (int r = 0; r < 4; ++r)
        swb[wave][m * 16 + re + r] = s[m][r];
  }
  __builtin_amdgcn_s_barrier();
  {
    const int slice = (ct & 1) * 8 + ks * 2 + wc;
    float* sp = sjp + ((size_t)slice * Bq + b) * Nq + i0 + wm * 64;
    sp[lane] = swb[wave][lane];
  }
}

// ---- sjv[b,i] = sb[b,i] + (sum of 16 partial slices) / t[b,i] ----
__global__ void k_sjsum(const float* __restrict__ sbA, const float* __restrict__ tA,
                        const float* __restrict__ sjp, float* __restrict__ sjvA) {
  int idx = blockIdx.x * 256 + threadIdx.x;
  float s = 0.f;
#pragma unroll
  for (int sl = 0; sl < 16; ++sl) s += sjp[(size_t)sl * Bq * Nq + idx];
  sjvA[idx] = sbA[idx] + s / tA[idx];
}

// ---- out[b,i,:] = softmax_j( mask(bm, lrelu(si[b,i] + sjv[b,j])) ) ----
__global__ void k_softmax(const unsigned* __restrict__ bm, const float* __restrict__ siA,
                          const float* __restrict__ sjvA, float* __restrict__ out) {
  const int b = blockIdx.y, i = blockIdx.x, tid = threadIdx.x;
  const float siv = siA[(size_t)b * Nq + i];
  const unsigned* brow = bm + (size_t)i * 64;
  const float* sjb = sjvA + (size_t)b * Nq;
  const int bit = tid & 31;
  float sc[8];
  float mx = -3.0e38f;
#pragma unroll
  for (int s = 0; s < 8; ++s) {
    int j = s * 256 + tid;
    float v = siv + sjb[j];
    v = v > 0.f ? v : 0.2f * v;
    unsigned wv = brow[j >> 5];
    v = ((wv >> bit) & 1u) ? v : -9.0e15f;
    sc[s] = v;
    mx = fmaxf(mx, v);
  }
#pragma unroll
  for (int o = 32; o >= 1; o >>= 1) mx = fmaxf(mx, __shfl_xor(mx, o, 64));
  __shared__ float redm[4], reds[4];
  const int wave = tid >> 6, lane = tid & 63;
  if (lane == 0) redm[wave] = mx;
  __syncthreads();
  mx = fmaxf(fmaxf(redm[0], redm[1]), fmaxf(redm[2], redm[3]));
  float sum = 0.f, ex[8];
#pragma unroll
  for (int s = 0; s < 8; ++s) { ex[s] = expf(sc[s] - mx); sum += ex[s]; }
#pragma unroll
  for (int o = 32; o >= 1; o >>= 1) sum += __shfl_xor(sum, o, 64);
  if (lane == 0) reds[wave] = sum;
  __syncthreads();
  sum = reds[0] + reds[1] + reds[2] + reds[3];
  float inv = 1.f / sum;
  float* orow = out + ((size_t)b * Nq + i) * Nq;
#pragma unroll
  for (int s = 0; s < 8; ++s) orow[s * 256 + tid] = ex[s] * inv;
}

extern "C" void kernel_launch(void* const* d_in, const int* in_sizes, int n_in,
                              void* d_out, int out_size, void* d_ws, size_t ws_size,
                              hipStream_t stream) {
  const float* x = (const float*)d_in[0];
  const int* adj = (const int*)d_in[1];
  const float* W = (const float*)d_in[2];
  const float* a = (const float*)d_in[3];
  float* out = (float*)d_out;

  char* ws = (char*)d_ws;
  size_t off = 0;
  auto alloc = [&](size_t bytes) -> void* {
    void* p = ws + off;
    off += (bytes + 255) & ~(size_t)255;
    return p;
  };
  float* w123 = (float*)alloc(3 * DINq * sizeof(float));
  float* WT = (float*)alloc((size_t)DINq * DINq * sizeof(float));
  float* tA = (float*)alloc((size_t)Bq * Nq * sizeof(float));
  float* siA = (float*)alloc((size_t)Bq * Nq * sizeof(float));
  float* sbA = (float*)alloc((size_t)Bq * Nq * sizeof(float));
  float* sjvA = (float*)alloc((size_t)Bq * Nq * sizeof(float));
  float* sjp = (float*)alloc((size_t)16 * Bq * Nq * sizeof(float));
  unsigned short* Xhi = (unsigned short*)alloc((size_t)Nq * Nq * 2);
  unsigned short* Xlo = (unsigned short*)alloc((size_t)Nq * Nq * 2);
  unsigned* bm = (unsigned*)alloc((size_t)Nq * 64 * sizeof(unsigned));

  k_prep<<<dim3(1), dim3(1024), 0, stream>>>(W, a, w123);
  k_transposeW<<<dim3(DINq), dim3(DINq), 0, stream>>>(W, WT);
  k_hX<<<dim3(Nq / 32, Bq), dim3(256), 0, stream>>>(x, WT, w123, Xhi, Xlo, tA, siA, sbA);
  k_mask<<<dim3(Nq * 64 / 256), dim3(256), 0, stream>>>(adj, bm);
  k_gemm<<<dim3(1024), dim3(256), 0, stream>>>(bm, Xhi, Xlo, sjp);
  k_sjsum<<<dim3(Bq * Nq / 256), dim3(256), 0, stream>>>(sbA, tA, sjp, sjvA);
  k_softmax<<<dim3(Nq, Bq), dim3(256), 0, stream>>>(bm, siA, sjvA, out);
}